// Round 3
// baseline (350.559 us; speedup 1.0000x reference)
//
#include <hip/hip_runtime.h>
#include <math.h>

namespace {

constexpr int Bb   = 128;
constexpr int Ss   = 196;
constexpr int DIN  = 512;
constexpr int Hh   = 8;
constexpr int DKc  = 32;
constexpr int DVc  = 128;
constexpr int QKVD = 1536;   // H*(2*DK+DV)
constexpr int PIN  = 1024;   // H*DV
constexpr int Mrows = Bb * Ss; // 25088
constexpr float EPSc   = 1e-3f;
constexpr float SCALEc = 0.17677669529663687f; // 32^-0.5

typedef __bf16 bf16x8 __attribute__((ext_vector_type(8)));
typedef __bf16 bf16x4 __attribute__((ext_vector_type(4)));
typedef float  f32x4  __attribute__((ext_vector_type(4)));

// VT layout: [bh][quarter(4)][ 8192 elems ], quarter row stride 232 elems.
constexpr int VT_STRIDE = 232;                 // elems; 464 B = 16B-aligned, 2-way banks
constexpr size_t VT_QELEMS = 8192;             // padded quarter (32 rows x 232 = 7424 used)
constexpr size_t VT_BH = 4 * VT_QELEMS;        // 32768 elems per (b,h)

__device__ __forceinline__ void gl_lds16(const void* g, void* l) {
    __builtin_amdgcn_global_load_lds(
        (const __attribute__((address_space(1))) void*)g,
        (__attribute__((address_space(3))) void*)l, 16, 0, 0);
}

// ---------------- fp32 -> bf16 elementwise convert (x) ----------------
__global__ __launch_bounds__(256)
void cvt_f32_bf16(const float* __restrict__ in, __bf16* __restrict__ out, int n4)
{
    int i = blockIdx.x * 256 + threadIdx.x;
    if (i < n4) {
        float4 v = ((const float4*)in)[i];
        bf16x4 o = { (__bf16)v.x, (__bf16)v.y, (__bf16)v.z, (__bf16)v.w };
        ((bf16x4*)out)[i] = o;
    }
}

// ---------------- W[K][N] fp32 -> WT[N][K] bf16 ----------------
__global__ __launch_bounds__(256)
void transpose_cvt(const float* __restrict__ W, __bf16* __restrict__ WT, int K, int N)
{
    __shared__ float tile[32][33];
    const int n0 = blockIdx.x * 32, k0 = blockIdx.y * 32;
    const int tx = threadIdx.x & 31, ty = threadIdx.x >> 5;
#pragma unroll
    for (int i = ty; i < 32; i += 8)
        tile[i][tx] = W[(size_t)(k0 + i) * N + n0 + tx];
    __syncthreads();
#pragma unroll
    for (int i = ty; i < 32; i += 8)
        WT[(size_t)(n0 + i) * K + k0 + tx] = (__bf16)tile[tx][i];
}

// ---------------- GEMM1: x@Wqkv + BN, scatter epilogue ----------------
// BK=64 via two [128][32] sub-panels (64 B row stride preserved -> no new bank
// conflicts, gl_lds dests stay linear). Half the barriers, 32 MFMA per pair.
// Q/K channels -> qkvO bf16 (nt stores); V channels -> VTp (nt packed stores).
__global__ __launch_bounds__(256)
void gemm1_bn_scatter(const __bf16* __restrict__ A, const __bf16* __restrict__ BT,
                      const float* __restrict__ bias, const float* __restrict__ gamma,
                      const float* __restrict__ beta, const float* __restrict__ mean,
                      const float* __restrict__ var,
                      __bf16* __restrict__ qkvO, __bf16* __restrict__ VTp)
{
    constexpr int N = QKVD, K = DIN;
    constexpr int BM = 128, BN = 128;
    __shared__ __bf16 As[2][BM * 32];   // panel kk: [128 rows][32 cols]
    __shared__ __bf16 Bs[2][BN * 32];

    const int t    = threadIdx.x;
    const int wave = t >> 6;
    const int lane = t & 63;
    const int lr   = lane & 15;
    const int q    = lane >> 4;

    constexpr int ntiles = N / BN;           // 12
    // T1: bijective XCD swizzle (nwg = 2352, divisible by 8) -> each XCD gets a
    // contiguous chunk; the 12 n-tiles sharing an A-panel stay on one XCD L2.
    constexpr int nwg = 196 * ntiles;
    const int bid = (blockIdx.x & 7) * (nwg >> 3) + (blockIdx.x >> 3);
    const int m0 = (bid / ntiles) * BM;
    const int n0 = (bid % ntiles) * BN;
    const int wm = (wave & 1) * 64;
    const int wn = (wave >> 1) * 64;

    const __bf16* aG0 = A  + (size_t)(m0 + (t >> 2)) * K + (t & 3) * 8;
    const __bf16* aG1 = aG0 + (size_t)64 * K;
    const __bf16* bG0 = BT + (size_t)(n0 + (t >> 2)) * K + (t & 3) * 8;
    const __bf16* bG1 = bG0 + (size_t)64 * K;
    char* lA = (char*)As + wave * 1024;      // rows 16w..16w+15 of panel 0
    char* lB = (char*)Bs + wave * 1024;

    f32x4 acc[4][4] = {};

    for (int k0 = 0; k0 < K; k0 += 64) {
        gl_lds16(aG0 + k0,      lA);
        gl_lds16(aG1 + k0,      lA + 4096);
        gl_lds16(aG0 + k0 + 32, lA + 8192);
        gl_lds16(aG1 + k0 + 32, lA + 8192 + 4096);
        gl_lds16(bG0 + k0,      lB);
        gl_lds16(bG1 + k0,      lB + 4096);
        gl_lds16(bG0 + k0 + 32, lB + 8192);
        gl_lds16(bG1 + k0 + 32, lB + 8192 + 4096);
        __syncthreads();
#pragma unroll
        for (int kk = 0; kk < 2; ++kk) {
            bf16x8 aF[4], bF[4];
#pragma unroll
            for (int i = 0; i < 4; ++i)
                aF[i] = *(const bf16x8*)(&As[kk][(wm + i * 16 + lr) * 32 + q * 8]);
#pragma unroll
            for (int j = 0; j < 4; ++j)
                bF[j] = *(const bf16x8*)(&Bs[kk][(wn + j * 16 + lr) * 32 + q * 8]);
#pragma unroll
            for (int i = 0; i < 4; ++i)
#pragma unroll
                for (int j = 0; j < 4; ++j)
                    acc[i][j] = __builtin_amdgcn_mfma_f32_16x16x32_bf16(
                        aF[i], bF[j], acc[i][j], 0, 0, 0);
        }
        __syncthreads();
    }

    // rows of this thread: mrow(i) = m0+wm+i*16+q*4 (+r). 4-aligned, 196|4 => never crosses b.
    int bidx[4], sidx[4];
#pragma unroll
    for (int i = 0; i < 4; ++i) {
        int mrow = m0 + wm + i * 16 + q * 4;
        bidx[i] = mrow / 196;
        sidx[i] = mrow - bidx[i] * 196;
    }
#pragma unroll
    for (int j = 0; j < 4; ++j) {
        const int n  = n0 + wn + j * 16 + lr;
        const int h  = n / 192;
        const int ch = n - h * 192;
        const float s  = gamma[n] * rsqrtf(var[n] + EPSc);
        const float tv = fmaf(bias[n] - mean[n], s, beta[n]);
        if (ch < 64) {
            // Q/K -> qkv bf16 (scattered b16 nt stores: avoid L2 write-allocate RMW)
#pragma unroll
            for (int i = 0; i < 4; ++i) {
                const int mrow = m0 + wm + i * 16 + q * 4;
#pragma unroll
                for (int r = 0; r < 4; ++r)
                    __builtin_nontemporal_store(
                        (__bf16)fmaf(acc[i][j][r], s, tv),
                        &qkvO[(size_t)(mrow + r) * N + n]);
            }
        } else {
            // V -> VTp (packed 4-s bf16 nt stores)
            const int d = ch - 64;
#pragma unroll
            for (int i = 0; i < 4; ++i) {
                const size_t base = (size_t)(bidx[i] * 8 + h) * VT_BH
                                  + (size_t)(d >> 5) * VT_QELEMS
                                  + (size_t)(d & 31) * VT_STRIDE + sidx[i];
                bf16x4 pk = { (__bf16)fmaf(acc[i][j][0], s, tv),
                              (__bf16)fmaf(acc[i][j][1], s, tv),
                              (__bf16)fmaf(acc[i][j][2], s, tv),
                              (__bf16)fmaf(acc[i][j][3], s, tv) };
                __builtin_nontemporal_store(pk, (bf16x4*)(VTp + base));
            }
        }
    }
}

// ---------------- generic bf16 MFMA GEMM + BN (fp32 out) — GEMM2 ----------------
// Same BK=64 split-panel structure + XCD swizzle + nt stores.
template<int N, int K>
__global__ __launch_bounds__(256)
void gemm_bn_mfma(const __bf16* __restrict__ A, const __bf16* __restrict__ BT,
                  const float* __restrict__ bias, const float* __restrict__ gamma,
                  const float* __restrict__ beta, const float* __restrict__ mean,
                  const float* __restrict__ var, float* __restrict__ C)
{
    constexpr int BM = 128, BN = 128;
    __shared__ __bf16 As[2][BM * 32];
    __shared__ __bf16 Bs[2][BN * 32];
    const int t    = threadIdx.x;
    const int wave = t >> 6;
    const int lane = t & 63;
    const int lr   = lane & 15;
    const int q    = lane >> 4;
    constexpr int ntiles = N / BN;
    constexpr int nwg = 196 * ntiles;        // 784 for N=512 -> divisible by 8
    const int bid = (blockIdx.x & 7) * (nwg >> 3) + (blockIdx.x >> 3);
    const int m0 = (bid / ntiles) * BM;
    const int n0 = (bid % ntiles) * BN;
    const int wm = (wave & 1) * 64;
    const int wn = (wave >> 1) * 64;
    const __bf16* aG0 = A  + (size_t)(m0 + (t >> 2)) * K + (t & 3) * 8;
    const __bf16* aG1 = aG0 + (size_t)64 * K;
    const __bf16* bG0 = BT + (size_t)(n0 + (t >> 2)) * K + (t & 3) * 8;
    const __bf16* bG1 = bG0 + (size_t)64 * K;
    char* lA = (char*)As + wave * 1024;
    char* lB = (char*)Bs + wave * 1024;
    f32x4 acc[4][4] = {};
    for (int k0 = 0; k0 < K; k0 += 64) {
        gl_lds16(aG0 + k0,      lA);
        gl_lds16(aG1 + k0,      lA + 4096);
        gl_lds16(aG0 + k0 + 32, lA + 8192);
        gl_lds16(aG1 + k0 + 32, lA + 8192 + 4096);
        gl_lds16(bG0 + k0,      lB);
        gl_lds16(bG1 + k0,      lB + 4096);
        gl_lds16(bG0 + k0 + 32, lB + 8192);
        gl_lds16(bG1 + k0 + 32, lB + 8192 + 4096);
        __syncthreads();
#pragma unroll
        for (int kk = 0; kk < 2; ++kk) {
            bf16x8 aF[4], bF[4];
#pragma unroll
            for (int i = 0; i < 4; ++i)
                aF[i] = *(const bf16x8*)(&As[kk][(wm + i * 16 + lr) * 32 + q * 8]);
#pragma unroll
            for (int j = 0; j < 4; ++j)
                bF[j] = *(const bf16x8*)(&Bs[kk][(wn + j * 16 + lr) * 32 + q * 8]);
#pragma unroll
            for (int i = 0; i < 4; ++i)
#pragma unroll
                for (int j = 0; j < 4; ++j)
                    acc[i][j] = __builtin_amdgcn_mfma_f32_16x16x32_bf16(
                        aF[i], bF[j], acc[i][j], 0, 0, 0);
        }
        __syncthreads();
    }
#pragma unroll
    for (int j = 0; j < 4; ++j) {
        const int n = n0 + wn + j * 16 + lr;
        const float s  = gamma[n] * rsqrtf(var[n] + EPSc);
        const float tv = fmaf(bias[n] - mean[n], s, beta[n]);
#pragma unroll
        for (int i = 0; i < 4; ++i) {
            const int mrow = m0 + wm + i * 16 + q * 4;
#pragma unroll
            for (int r = 0; r < 4; ++r)
                __builtin_nontemporal_store(
                    fmaf(acc[i][j][r], s, tv),
                    &C[(size_t)(mrow + r) * N + n]);
        }
    }
}

// ---------------- MFMA attention v2: one block per (b,h), 16 waves ----------------
// wave w owns q-tile qt = w (16 q-rows); 13 active tiles cover S=196 (pad to 208).
// K staged ONCE, V quarters streamed ONCE each (double-buffered, issue-early).
// LDS: Kb[208][40] (16640 B) | P: 13 x [16][232] (96512 B) | V dbuf 2x16384 = 145920 B
__global__ __launch_bounds__(1024)
void attn_mfma(const __bf16* __restrict__ qkv, const __bf16* __restrict__ VTp,
               __bf16* __restrict__ hidden)
{
    __shared__ __align__(16) char smem[145920];
    __bf16* Kb = (__bf16*)smem;

    const int t = threadIdx.x;
    const int wave = t >> 6, lane = t & 63;
    const int lr = lane & 15, q = lane >> 4;
    const int bh = blockIdx.x;
    const int b = bh >> 3, h = bh & 7;
    const __bf16* qkvb = qkv + (size_t)b * 196 * QKVD + h * 192;

    // ---- issue V quarter 0 stage FIRST so HBM latency drains under K staging ----
    const char* gV = (const char*)(VTp + (size_t)bh * VT_BH);
    char* ldsV = smem + 113152;                 // 2 x 16384 double buffer
    gl_lds16(gV + wave * 1024 + lane * 16, ldsV + wave * 1024);

    // ---- stage K once: rows s=0..195, ch 32..63 -> Kb[s][40] ----
    if (t < 196 * 4) {
        const int s = t >> 2, c = t & 3;
        bf16x8 v = *(const bf16x8*)(qkvb + (size_t)s * QKVD + 32 + c * 8);
        *(bf16x8*)(Kb + s * 40 + c * 8) = v;
    }

    __syncthreads();                            // K ready; barrier drains vmcnt -> V0 ready

    const int qt = wave;                        // q-tile; valid rows only for qt<=12
    const bool wactive = (qt <= 12);
    __bf16* Pw = (__bf16*)(smem + 16640 + (wactive ? qt : 0) * 7424);   // [16][232]

    if (wactive) {
        // Q fragment straight from global
        int sQ = qt * 16 + lr; if (sQ > 195) sQ = 195;
        bf16x8 aQ = *(const bf16x8*)(qkv + ((size_t)b * 196 + sQ) * QKVD + h * 192 + q * 8);

        f32x4 sc[13];
#pragma unroll
        for (int nt = 0; nt < 13; ++nt) {
            bf16x8 bK = *(const bf16x8*)(Kb + (nt * 16 + lr) * 40 + q * 8);
            f32x4 z = {0.f, 0.f, 0.f, 0.f};
            sc[nt] = __builtin_amdgcn_mfma_f32_16x16x32_bf16(aQ, bK, z, 0, 0, 0);
        }
        // ---- register softmax over the 208 cols (cols>=196 masked) ----
        float mrow[4] = {-1e30f, -1e30f, -1e30f, -1e30f};
#pragma unroll
        for (int nt = 0; nt < 13; ++nt) {
            const bool valid = (nt < 12) | (lr < 4);
#pragma unroll
            for (int r = 0; r < 4; ++r) {
                float x = sc[nt][r] * SCALEc;
                sc[nt][r] = x;
                if (valid) mrow[r] = fmaxf(mrow[r], x);
            }
        }
#pragma unroll
        for (int d = 1; d < 16; d <<= 1)
#pragma unroll
            for (int r = 0; r < 4; ++r)
                mrow[r] = fmaxf(mrow[r], __shfl_xor(mrow[r], d, 64));
        float l[4] = {0.f, 0.f, 0.f, 0.f};
#pragma unroll
        for (int nt = 0; nt < 13; ++nt) {
            const bool valid = (nt < 12) | (lr < 4);
#pragma unroll
            for (int r = 0; r < 4; ++r) {
                float e = valid ? __expf(sc[nt][r] - mrow[r]) : 0.f;
                sc[nt][r] = e;
                l[r] += e;
            }
        }
#pragma unroll
        for (int d = 1; d < 16; d <<= 1)
#pragma unroll
            for (int r = 0; r < 4; ++r)
                l[r] += __shfl_xor(l[r], d, 64);
        float inv[4];
#pragma unroll
        for (int r = 0; r < 4; ++r) inv[r] = 1.f / l[r];

        // ---- P to LDS in A-operand layout: P[m=quad*4+r][col] ----
#pragma unroll
        for (int nt = 0; nt < 13; ++nt)
#pragma unroll
            for (int r = 0; r < 4; ++r)
                Pw[(q * 4 + r) * 232 + nt * 16 + lr] = (__bf16)(sc[nt][r] * inv[r]);
        // zero cols 208..231 (PV k-loop reads through col 223)
        for (int idx = lane; idx < 16 * 24; idx += 64) {
            int row = idx & 15, cz = 208 + (idx >> 4);
            Pw[row * 232 + cz] = (__bf16)0.f;
        }
    }
    __syncthreads();                            // P ready (all 13 slots)

    // ---- PV over 4 dv-quarters; next quarter staged under current compute ----
    const int sbase = qt * 16 + q * 4;
    const bool sval = wactive && (sbase + 3 < 196);
    __bf16* hb = hidden + (size_t)b * 200704 + (size_t)h * 25088;

    for (int q4 = 0; q4 < 4; ++q4) {
        const __bf16* Vl = (const __bf16*)(ldsV + (q4 & 1) * 16384);
        if (q4 < 3)   // issue next quarter into the other buffer (drained by the barrier below)
            gl_lds16(gV + (size_t)(q4 + 1) * 16384 + wave * 1024 + lane * 16,
                     ldsV + ((q4 + 1) & 1) * 16384 + wave * 1024);
        if (wactive) {
            f32x4 o0 = {0.f, 0.f, 0.f, 0.f}, o1 = {0.f, 0.f, 0.f, 0.f};
#pragma unroll
            for (int kk = 0; kk < 7; ++kk) {
                bf16x8 aP = *(const bf16x8*)(Pw + lr * 232 + kk * 32 + q * 8);
                bf16x8 b0 = *(const bf16x8*)(Vl + lr * 232 + kk * 32 + q * 8);
                bf16x8 b1 = *(const bf16x8*)(Vl + (16 + lr) * 232 + kk * 32 + q * 8);
                o0 = __builtin_amdgcn_mfma_f32_16x16x32_bf16(aP, b0, o0, 0, 0, 0);
                o1 = __builtin_amdgcn_mfma_f32_16x16x32_bf16(aP, b1, o1, 0, 0, 0);
            }
            if (sval) {
#pragma unroll
                for (int nt2 = 0; nt2 < 2; ++nt2) {
                    f32x4 o = nt2 ? o1 : o0;
                    const int d = q4 * 32 + nt2 * 16 + lr;
                    bf16x4 pk;
#pragma unroll
                    for (int r = 0; r < 4; ++r) {
                        float x = o[r];
                        pk[r] = (__bf16)(x * fminf(fmaxf(x + 3.f, 0.f), 6.f) * (1.f / 6.f));
                    }
                    __builtin_nontemporal_store(pk, (bf16x4*)(hb + (size_t)d * 196 + sbase));
                }
            }
        }
        if (q4 < 3) __syncthreads();
    }
}

} // namespace

extern "C" void kernel_launch(void* const* d_in, const int* in_sizes, int n_in,
                              void* d_out, int out_size, void* d_ws, size_t ws_size,
                              hipStream_t stream)
{
    const float* x    = (const float*)d_in[0];
    const float* Wqkv = (const float*)d_in[1];
    const float* bqkv = (const float*)d_in[2];
    const float* g1   = (const float*)d_in[3];
    const float* be1  = (const float*)d_in[4];
    const float* mu1  = (const float*)d_in[5];
    const float* va1  = (const float*)d_in[6];
    const float* Wp   = (const float*)d_in[7];
    const float* bp   = (const float*)d_in[8];
    const float* g2   = (const float*)d_in[9];
    const float* be2  = (const float*)d_in[10];
    const float* mu2  = (const float*)d_in[11];
    const float* va2  = (const float*)d_in[12];

    // workspace layout (bytes)
    char* ws = (char*)d_ws;
    __bf16* qkv    = (__bf16*)ws;                    // 25088*1536*2 = 77,070,336
    __bf16* VTp    = (__bf16*)(ws + 77070336);       // 1024*32768*2 = 67,108,864
    __bf16* hidden = (__bf16*)(ws + 144179200);      // 25088*1024*2 = 51,380,224
    __bf16* xb     = (__bf16*)(ws + 195559424);      // 25088*512*2  = 25,690,112
    __bf16* WT1    = (__bf16*)(ws + 221249536);      // 1536*512*2
    __bf16* WT2    = (__bf16*)(ws + 222822400);      // 512*1024*2
    float*  out    = (float*)d_out;

    cvt_f32_bf16<<<dim3((Mrows * DIN / 4 + 255) / 256), dim3(256), 0, stream>>>(
        x, xb, Mrows * DIN / 4);
    transpose_cvt<<<dim3(QKVD / 32, DIN / 32), dim3(256), 0, stream>>>(Wqkv, WT1, DIN, QKVD);
    transpose_cvt<<<dim3(DIN / 32, PIN / 32), dim3(256), 0, stream>>>(Wp, WT2, PIN, DIN);

    // GEMM1 + BN -> qkv bf16 (Q,K) + VTp (V pre-transposed)
    gemm1_bn_scatter<<<dim3(196 * (QKVD / 128)), dim3(256), 0, stream>>>(
        xb, WT1, bqkv, g1, be1, mu1, va1, qkv, VTp);

    // MFMA attention -> hidden bf16 (scrambled layout); 1 block per (b,h), 16 waves
    attn_mfma<<<dim3(Bb * Hh), dim3(1024), 0, stream>>>(qkv, VTp, hidden);

    // GEMM2 + BN -> out fp32
    gemm_bn_mfma<DIN, PIN><<<dim3(196 * (DIN / 128)), dim3(256), 0, stream>>>(
        hidden, WT2, bp, g2, be2, mu2, va2, out);
}

// Round 4
// 289.851 us; speedup vs baseline: 1.2094x; 1.2094x over previous
//
#include <hip/hip_runtime.h>
#include <math.h>

namespace {

constexpr int Bb   = 128;
constexpr int Ss   = 196;
constexpr int DIN  = 512;
constexpr int Hh   = 8;
constexpr int DKc  = 32;
constexpr int DVc  = 128;
constexpr int QKVD = 1536;   // H*(2*DK+DV)
constexpr int PIN  = 1024;   // H*DV
constexpr int Mrows = Bb * Ss; // 25088
constexpr float EPSc   = 1e-3f;
constexpr float SCALEc = 0.17677669529663687f; // 32^-0.5

typedef __bf16 bf16x8 __attribute__((ext_vector_type(8)));
typedef __bf16 bf16x4 __attribute__((ext_vector_type(4)));
typedef float  f32x4  __attribute__((ext_vector_type(4)));

// VT layout: [bh][quarter(4)][ 8192 elems ], quarter row stride 232 elems.
constexpr int VT_STRIDE = 232;                 // elems; 464 B = 16B-aligned, 2-way banks
constexpr size_t VT_QELEMS = 8192;             // padded quarter (32 rows x 232 = 7424 used)
constexpr size_t VT_BH = 4 * VT_QELEMS;        // 32768 elems per (b,h)

__device__ __forceinline__ void gl_lds16(const void* g, void* l) {
    __builtin_amdgcn_global_load_lds(
        (const __attribute__((address_space(1))) void*)g,
        (__attribute__((address_space(3))) void*)l, 16, 0, 0);
}

// ---------------- fp32 -> bf16 elementwise convert (x) ----------------
__global__ __launch_bounds__(256)
void cvt_f32_bf16(const float* __restrict__ in, __bf16* __restrict__ out, int n4)
{
    int i = blockIdx.x * 256 + threadIdx.x;
    if (i < n4) {
        float4 v = ((const float4*)in)[i];
        bf16x4 o = { (__bf16)v.x, (__bf16)v.y, (__bf16)v.z, (__bf16)v.w };
        ((bf16x4*)out)[i] = o;
    }
}

// ---------------- W[K][N] fp32 -> WT[N][K] bf16 ----------------
__global__ __launch_bounds__(256)
void transpose_cvt(const float* __restrict__ W, __bf16* __restrict__ WT, int K, int N)
{
    __shared__ float tile[32][33];
    const int n0 = blockIdx.x * 32, k0 = blockIdx.y * 32;
    const int tx = threadIdx.x & 31, ty = threadIdx.x >> 5;
#pragma unroll
    for (int i = ty; i < 32; i += 8)
        tile[i][tx] = W[(size_t)(k0 + i) * N + n0 + tx];
    __syncthreads();
#pragma unroll
    for (int i = ty; i < 32; i += 8)
        WT[(size_t)(n0 + i) * K + k0 + tx] = (__bf16)tile[tx][i];
}

// ---------------- GEMM1: x@Wqkv + BN, LDS-shuffle epilogue ----------------
// BK=64 split-panel main loop (as r3). Epilogue stages the post-BN tile in LDS
// (overlaying As/Bs) and writes out full-line coalesced:
//   QK cols (64-aligned 64-wide runs) -> qkv via bf16x8, 8 lanes = 1 full line.
//   V cols -> VTp via bf16x8 along s (col-major LDS region).
// Tile types by n0%384: 0:{QK c0..63, V c64..127} 128:{V c0..63, QK c64..127}
//                       256:{V all 128} — 16-col wave groups never straddle.
__global__ __launch_bounds__(256)
void gemm1_bn_scatter(const __bf16* __restrict__ A, const __bf16* __restrict__ BT,
                      const float* __restrict__ bias, const float* __restrict__ gamma,
                      const float* __restrict__ beta, const float* __restrict__ mean,
                      const float* __restrict__ var,
                      __bf16* __restrict__ qkvO, __bf16* __restrict__ VTp)
{
    constexpr int N = QKVD, K = DIN;
    constexpr int BM = 128, BN = 128;
    // 35840 B: main loop uses [0,32768) as As|Bs; epilogue overlays
    // qkreg [128][72] @0 (18432 B) + vreg [64][136] @18432 (17408 B),
    // or vreg [128][136] @0 for all-V tiles (34816 B).
    __shared__ __align__(16) char sm[35840];
    __bf16* Asp = (__bf16*)sm;                 // [2][128*32]
    __bf16* Bsp = (__bf16*)(sm + 16384);       // [2][128*32]

    const int t    = threadIdx.x;
    const int wave = t >> 6;
    const int lane = t & 63;
    const int lr   = lane & 15;
    const int q    = lane >> 4;

    constexpr int ntiles = N / BN;           // 12
    // T1: bijective XCD swizzle (nwg = 2352, divisible by 8).
    constexpr int nwg = 196 * ntiles;
    const int bid = (blockIdx.x & 7) * (nwg >> 3) + (blockIdx.x >> 3);
    const int m0 = (bid / ntiles) * BM;
    const int n0 = (bid % ntiles) * BN;
    const int wm = (wave & 1) * 64;
    const int wn = (wave >> 1) * 64;

    const __bf16* aG0 = A  + (size_t)(m0 + (t >> 2)) * K + (t & 3) * 8;
    const __bf16* aG1 = aG0 + (size_t)64 * K;
    const __bf16* bG0 = BT + (size_t)(n0 + (t >> 2)) * K + (t & 3) * 8;
    const __bf16* bG1 = bG0 + (size_t)64 * K;
    char* lA = sm + wave * 1024;
    char* lB = sm + 16384 + wave * 1024;

    f32x4 acc[4][4] = {};

    for (int k0 = 0; k0 < K; k0 += 64) {
        gl_lds16(aG0 + k0,      lA);
        gl_lds16(aG1 + k0,      lA + 4096);
        gl_lds16(aG0 + k0 + 32, lA + 8192);
        gl_lds16(aG1 + k0 + 32, lA + 8192 + 4096);
        gl_lds16(bG0 + k0,      lB);
        gl_lds16(bG1 + k0,      lB + 4096);
        gl_lds16(bG0 + k0 + 32, lB + 8192);
        gl_lds16(bG1 + k0 + 32, lB + 8192 + 4096);
        __syncthreads();
#pragma unroll
        for (int kk = 0; kk < 2; ++kk) {
            bf16x8 aF[4], bF[4];
#pragma unroll
            for (int i = 0; i < 4; ++i)
                aF[i] = *(const bf16x8*)(Asp + kk * 4096 + (wm + i * 16 + lr) * 32 + q * 8);
#pragma unroll
            for (int j = 0; j < 4; ++j)
                bF[j] = *(const bf16x8*)(Bsp + kk * 4096 + (wn + j * 16 + lr) * 32 + q * 8);
#pragma unroll
            for (int i = 0; i < 4; ++i)
#pragma unroll
                for (int j = 0; j < 4; ++j)
                    acc[i][j] = __builtin_amdgcn_mfma_f32_16x16x32_bf16(
                        aF[i], bF[j], acc[i][j], 0, 0, 0);
        }
        __syncthreads();
    }

    // ---- epilogue: BN + stage to LDS ----
    const int tmod = n0 % 384;
    const int cq0  = (tmod == 0) ? 0 : (tmod == 128 ? 64 : -1);
    const int vc0  = (tmod == 0) ? 64 : 0;
    const int nv   = (tmod == 256) ? 128 : 64;
    const bool qk_wave = (tmod == 0) ? (wn == 0) : (tmod == 128 ? (wn == 64) : false);

    __bf16* qkreg = (__bf16*)sm;                                   // [128][72]
    __bf16* vreg  = (__bf16*)(sm + ((nv == 128) ? 0 : 18432));     // [nv][136] col-major
    const int vbase = (nv == 128) ? wn : 0;

#pragma unroll
    for (int j = 0; j < 4; ++j) {
        const int n = n0 + wn + j * 16 + lr;
        const float s  = gamma[n] * rsqrtf(var[n] + EPSc);
        const float tv = fmaf(bias[n] - mean[n], s, beta[n]);
        if (qk_wave) {
#pragma unroll
            for (int i = 0; i < 4; ++i) {
                const int row = wm + i * 16 + q * 4;
#pragma unroll
                for (int r = 0; r < 4; ++r)
                    qkreg[(row + r) * 72 + j * 16 + lr] = (__bf16)fmaf(acc[i][j][r], s, tv);
            }
        } else {
#pragma unroll
            for (int i = 0; i < 4; ++i) {
                bf16x4 pk = { (__bf16)fmaf(acc[i][j][0], s, tv),
                              (__bf16)fmaf(acc[i][j][1], s, tv),
                              (__bf16)fmaf(acc[i][j][2], s, tv),
                              (__bf16)fmaf(acc[i][j][3], s, tv) };
                *(bf16x4*)(vreg + (vbase + j * 16 + lr) * 136 + wm + i * 16 + q * 4) = pk;
            }
        }
    }
    __syncthreads();

    // ---- QK write-out: full 128 B lines (8 lanes x 16 B) ----
    if (cq0 >= 0) {
#pragma unroll
        for (int rr = 0; rr < 4; ++rr) {
            const int row = rr * 32 + (t >> 3);
            const int l   = t & 7;
            bf16x8 vv = *(const bf16x8*)(qkreg + row * 72 + l * 8);
            *(bf16x8*)(qkvO + (size_t)(m0 + row) * N + n0 + cq0 + l * 8) = vv;
        }
    }
    // ---- V write-out: 16 B along s into VTp ----
    const int iters = (nv * 16) / 256;   // 4 or 8
    for (int it = 0; it < iters; ++it) {
        const int a  = it * 256 + t;
        const int cl = a >> 4;           // local V col
        const int r0 = (a & 15) * 8;     // tile row of first elem
        const int n  = n0 + vc0 + cl;
        const int h  = n / 192;
        const int d  = n - h * 192 - 64;
        const int mr = m0 + r0;
        const int b_ = mr / 196;
        const int s0 = mr - b_ * 196;
        __bf16* dst0 = VTp + (size_t)(b_ * 8 + h) * VT_BH
                     + (size_t)(d >> 5) * VT_QELEMS + (size_t)(d & 31) * VT_STRIDE;
        bf16x8 vv = *(const bf16x8*)(vreg + cl * 136 + r0);
        if (s0 <= 188) {
            *(bf16x8*)(dst0 + s0) = vv;
        } else {
            // chunk straddles a batch boundary (s wraps at 196): scalar split
#pragma unroll
            for (int e = 0; e < 8; ++e) {
                int se = s0 + e;
                __bf16* dst = dst0;
                if (se >= 196) { se -= 196; dst += 8 * VT_BH; }
                dst[se] = vv[e];
            }
        }
    }
}

// ---------------- generic bf16 MFMA GEMM + BN (fp32 out) — GEMM2 ----------------
// BK=64 split-panel + XCD swizzle; regular (cached) stores.
template<int N, int K>
__global__ __launch_bounds__(256)
void gemm_bn_mfma(const __bf16* __restrict__ A, const __bf16* __restrict__ BT,
                  const float* __restrict__ bias, const float* __restrict__ gamma,
                  const float* __restrict__ beta, const float* __restrict__ mean,
                  const float* __restrict__ var, float* __restrict__ C)
{
    constexpr int BM = 128, BN = 128;
    __shared__ __bf16 As[2][BM * 32];
    __shared__ __bf16 Bs[2][BN * 32];
    const int t    = threadIdx.x;
    const int wave = t >> 6;
    const int lane = t & 63;
    const int lr   = lane & 15;
    const int q    = lane >> 4;
    constexpr int ntiles = N / BN;
    constexpr int nwg = 196 * ntiles;        // 784 for N=512 -> divisible by 8
    const int bid = (blockIdx.x & 7) * (nwg >> 3) + (blockIdx.x >> 3);
    const int m0 = (bid / ntiles) * BM;
    const int n0 = (bid % ntiles) * BN;
    const int wm = (wave & 1) * 64;
    const int wn = (wave >> 1) * 64;
    const __bf16* aG0 = A  + (size_t)(m0 + (t >> 2)) * K + (t & 3) * 8;
    const __bf16* aG1 = aG0 + (size_t)64 * K;
    const __bf16* bG0 = BT + (size_t)(n0 + (t >> 2)) * K + (t & 3) * 8;
    const __bf16* bG1 = bG0 + (size_t)64 * K;
    char* lA = (char*)As + wave * 1024;
    char* lB = (char*)Bs + wave * 1024;
    f32x4 acc[4][4] = {};
    for (int k0 = 0; k0 < K; k0 += 64) {
        gl_lds16(aG0 + k0,      lA);
        gl_lds16(aG1 + k0,      lA + 4096);
        gl_lds16(aG0 + k0 + 32, lA + 8192);
        gl_lds16(aG1 + k0 + 32, lA + 8192 + 4096);
        gl_lds16(bG0 + k0,      lB);
        gl_lds16(bG1 + k0,      lB + 4096);
        gl_lds16(bG0 + k0 + 32, lB + 8192);
        gl_lds16(bG1 + k0 + 32, lB + 8192 + 4096);
        __syncthreads();
#pragma unroll
        for (int kk = 0; kk < 2; ++kk) {
            bf16x8 aF[4], bF[4];
#pragma unroll
            for (int i = 0; i < 4; ++i)
                aF[i] = *(const bf16x8*)(&As[kk][(wm + i * 16 + lr) * 32 + q * 8]);
#pragma unroll
            for (int j = 0; j < 4; ++j)
                bF[j] = *(const bf16x8*)(&Bs[kk][(wn + j * 16 + lr) * 32 + q * 8]);
#pragma unroll
            for (int i = 0; i < 4; ++i)
#pragma unroll
                for (int j = 0; j < 4; ++j)
                    acc[i][j] = __builtin_amdgcn_mfma_f32_16x16x32_bf16(
                        aF[i], bF[j], acc[i][j], 0, 0, 0);
        }
        __syncthreads();
    }
#pragma unroll
    for (int j = 0; j < 4; ++j) {
        const int n = n0 + wn + j * 16 + lr;
        const float s  = gamma[n] * rsqrtf(var[n] + EPSc);
        const float tv = fmaf(bias[n] - mean[n], s, beta[n]);
#pragma unroll
        for (int i = 0; i < 4; ++i) {
            const int mrow = m0 + wm + i * 16 + q * 4;
#pragma unroll
            for (int r = 0; r < 4; ++r)
                C[(size_t)(mrow + r) * N + n] = fmaf(acc[i][j][r], s, tv);
        }
    }
}

// ---------------- MFMA attention v2: one block per (b,h), 16 waves ----------------
// wave w owns q-tile qt = w (16 q-rows); 13 active tiles cover S=196 (pad to 208).
// K staged ONCE, V quarters streamed ONCE each (double-buffered, issue-early).
// LDS: Kb[208][40] (16640 B) | P: 13 x [16][232] (96512 B) | V dbuf 2x16384 = 145920 B
__global__ __launch_bounds__(1024)
void attn_mfma(const __bf16* __restrict__ qkv, const __bf16* __restrict__ VTp,
               __bf16* __restrict__ hidden)
{
    __shared__ __align__(16) char smem[145920];
    __bf16* Kb = (__bf16*)smem;

    const int t = threadIdx.x;
    const int wave = t >> 6, lane = t & 63;
    const int lr = lane & 15, q = lane >> 4;
    const int bh = blockIdx.x;
    const int b = bh >> 3, h = bh & 7;
    const __bf16* qkvb = qkv + (size_t)b * 196 * QKVD + h * 192;

    // ---- issue V quarter 0 stage FIRST so HBM latency drains under K staging ----
    const char* gV = (const char*)(VTp + (size_t)bh * VT_BH);
    char* ldsV = smem + 113152;                 // 2 x 16384 double buffer
    gl_lds16(gV + wave * 1024 + lane * 16, ldsV + wave * 1024);

    // ---- stage K once: rows s=0..195, ch 32..63 -> Kb[s][40] ----
    if (t < 196 * 4) {
        const int s = t >> 2, c = t & 3;
        bf16x8 v = *(const bf16x8*)(qkvb + (size_t)s * QKVD + 32 + c * 8);
        *(bf16x8*)(Kb + s * 40 + c * 8) = v;
    }

    __syncthreads();                            // K ready; barrier drains vmcnt -> V0 ready

    const int qt = wave;                        // q-tile; valid rows only for qt<=12
    const bool wactive = (qt <= 12);
    __bf16* Pw = (__bf16*)(smem + 16640 + (wactive ? qt : 0) * 7424);   // [16][232]

    if (wactive) {
        // Q fragment straight from global
        int sQ = qt * 16 + lr; if (sQ > 195) sQ = 195;
        bf16x8 aQ = *(const bf16x8*)(qkv + ((size_t)b * 196 + sQ) * QKVD + h * 192 + q * 8);

        f32x4 sc[13];
#pragma unroll
        for (int nt = 0; nt < 13; ++nt) {
            bf16x8 bK = *(const bf16x8*)(Kb + (nt * 16 + lr) * 40 + q * 8);
            f32x4 z = {0.f, 0.f, 0.f, 0.f};
            sc[nt] = __builtin_amdgcn_mfma_f32_16x16x32_bf16(aQ, bK, z, 0, 0, 0);
        }
        // ---- register softmax over the 208 cols (cols>=196 masked) ----
        float mrow[4] = {-1e30f, -1e30f, -1e30f, -1e30f};
#pragma unroll
        for (int nt = 0; nt < 13; ++nt) {
            const bool valid = (nt < 12) | (lr < 4);
#pragma unroll
            for (int r = 0; r < 4; ++r) {
                float x = sc[nt][r] * SCALEc;
                sc[nt][r] = x;
                if (valid) mrow[r] = fmaxf(mrow[r], x);
            }
        }
#pragma unroll
        for (int d = 1; d < 16; d <<= 1)
#pragma unroll
            for (int r = 0; r < 4; ++r)
                mrow[r] = fmaxf(mrow[r], __shfl_xor(mrow[r], d, 64));
        float l[4] = {0.f, 0.f, 0.f, 0.f};
#pragma unroll
        for (int nt = 0; nt < 13; ++nt) {
            const bool valid = (nt < 12) | (lr < 4);
#pragma unroll
            for (int r = 0; r < 4; ++r) {
                float e = valid ? __expf(sc[nt][r] - mrow[r]) : 0.f;
                sc[nt][r] = e;
                l[r] += e;
            }
        }
#pragma unroll
        for (int d = 1; d < 16; d <<= 1)
#pragma unroll
            for (int r = 0; r < 4; ++r)
                l[r] += __shfl_xor(l[r], d, 64);
        float inv[4];
#pragma unroll
        for (int r = 0; r < 4; ++r) inv[r] = 1.f / l[r];

        // ---- P to LDS in A-operand layout: P[m=quad*4+r][col] ----
#pragma unroll
        for (int nt = 0; nt < 13; ++nt)
#pragma unroll
            for (int r = 0; r < 4; ++r)
                Pw[(q * 4 + r) * 232 + nt * 16 + lr] = (__bf16)(sc[nt][r] * inv[r]);
        // zero cols 208..231 (PV k-loop reads through col 223)
        for (int idx = lane; idx < 16 * 24; idx += 64) {
            int row = idx & 15, cz = 208 + (idx >> 4);
            Pw[row * 232 + cz] = (__bf16)0.f;
        }
    }
    __syncthreads();                            // P ready (all 13 slots)

    // ---- PV over 4 dv-quarters; next quarter staged under current compute ----
    const int sbase = qt * 16 + q * 4;
    const bool sval = wactive && (sbase + 3 < 196);
    __bf16* hb = hidden + (size_t)b * 200704 + (size_t)h * 25088;

    for (int q4 = 0; q4 < 4; ++q4) {
        const __bf16* Vl = (const __bf16*)(ldsV + (q4 & 1) * 16384);
        if (q4 < 3)   // issue next quarter into the other buffer (drained by the barrier below)
            gl_lds16(gV + (size_t)(q4 + 1) * 16384 + wave * 1024 + lane * 16,
                     ldsV + ((q4 + 1) & 1) * 16384 + wave * 1024);
        if (wactive) {
            f32x4 o0 = {0.f, 0.f, 0.f, 0.f}, o1 = {0.f, 0.f, 0.f, 0.f};
#pragma unroll
            for (int kk = 0; kk < 7; ++kk) {
                bf16x8 aP = *(const bf16x8*)(Pw + lr * 232 + kk * 32 + q * 8);
                bf16x8 b0 = *(const bf16x8*)(Vl + lr * 232 + kk * 32 + q * 8);
                bf16x8 b1 = *(const bf16x8*)(Vl + (16 + lr) * 232 + kk * 32 + q * 8);
                o0 = __builtin_amdgcn_mfma_f32_16x16x32_bf16(aP, b0, o0, 0, 0, 0);
                o1 = __builtin_amdgcn_mfma_f32_16x16x32_bf16(aP, b1, o1, 0, 0, 0);
            }
            if (sval) {
#pragma unroll
                for (int nt2 = 0; nt2 < 2; ++nt2) {
                    f32x4 o = nt2 ? o1 : o0;
                    const int d = q4 * 32 + nt2 * 16 + lr;
                    bf16x4 pk;
#pragma unroll
                    for (int r = 0; r < 4; ++r) {
                        float x = o[r];
                        pk[r] = (__bf16)(x * fminf(fmaxf(x + 3.f, 0.f), 6.f) * (1.f / 6.f));
                    }
                    *(bf16x4*)(hb + (size_t)d * 196 + sbase) = pk;
                }
            }
        }
        if (q4 < 3) __syncthreads();
    }
}

} // namespace

extern "C" void kernel_launch(void* const* d_in, const int* in_sizes, int n_in,
                              void* d_out, int out_size, void* d_ws, size_t ws_size,
                              hipStream_t stream)
{
    const float* x    = (const float*)d_in[0];
    const float* Wqkv = (const float*)d_in[1];
    const float* bqkv = (const float*)d_in[2];
    const float* g1   = (const float*)d_in[3];
    const float* be1  = (const float*)d_in[4];
    const float* mu1  = (const float*)d_in[5];
    const float* va1  = (const float*)d_in[6];
    const float* Wp   = (const float*)d_in[7];
    const float* bp   = (const float*)d_in[8];
    const float* g2   = (const float*)d_in[9];
    const float* be2  = (const float*)d_in[10];
    const float* mu2  = (const float*)d_in[11];
    const float* va2  = (const float*)d_in[12];

    // workspace layout (bytes)
    char* ws = (char*)d_ws;
    __bf16* qkv    = (__bf16*)ws;                    // 25088*1536*2 = 77,070,336
    __bf16* VTp    = (__bf16*)(ws + 77070336);       // 1024*32768*2 = 67,108,864
    __bf16* hidden = (__bf16*)(ws + 144179200);      // 25088*1024*2 = 51,380,224
    __bf16* xb     = (__bf16*)(ws + 195559424);      // 25088*512*2  = 25,690,112
    __bf16* WT1    = (__bf16*)(ws + 221249536);      // 1536*512*2
    __bf16* WT2    = (__bf16*)(ws + 222822400);      // 512*1024*2
    float*  out    = (float*)d_out;

    cvt_f32_bf16<<<dim3((Mrows * DIN / 4 + 255) / 256), dim3(256), 0, stream>>>(
        x, xb, Mrows * DIN / 4);
    transpose_cvt<<<dim3(QKVD / 32, DIN / 32), dim3(256), 0, stream>>>(Wqkv, WT1, DIN, QKVD);
    transpose_cvt<<<dim3(DIN / 32, PIN / 32), dim3(256), 0, stream>>>(Wp, WT2, PIN, DIN);

    // GEMM1 + BN -> qkv bf16 (Q,K) + VTp (V pre-transposed)
    gemm1_bn_scatter<<<dim3(196 * (QKVD / 128)), dim3(256), 0, stream>>>(
        xb, WT1, bqkv, g1, be1, mu1, va1, qkv, VTp);

    // MFMA attention -> hidden bf16 (scrambled layout); 1 block per (b,h), 16 waves
    attn_mfma<<<dim3(Bb * Hh), dim3(1024), 0, stream>>>(qkv, VTp, hidden);

    // GEMM2 + BN -> out fp32
    gemm_bn_mfma<DIN, PIN><<<dim3(196 * (DIN / 128)), dim3(256), 0, stream>>>(
        hidden, WT2, bp, g2, be2, mu2, va2, out);
}

// Round 5
// 281.764 us; speedup vs baseline: 1.2442x; 1.0287x over previous
//
#include <hip/hip_runtime.h>
#include <math.h>

namespace {

constexpr int Bb   = 128;
constexpr int Ss   = 196;
constexpr int DIN  = 512;
constexpr int Hh   = 8;
constexpr int DKc  = 32;
constexpr int DVc  = 128;
constexpr int QKVD = 1536;   // H*(2*DK+DV)
constexpr int PIN  = 1024;   // H*DV
constexpr int Mrows = Bb * Ss; // 25088
constexpr float EPSc   = 1e-3f;
constexpr float SCALEc = 0.17677669529663687f; // 32^-0.5

typedef __bf16 bf16x8 __attribute__((ext_vector_type(8)));
typedef __bf16 bf16x4 __attribute__((ext_vector_type(4)));
typedef float  f32x4  __attribute__((ext_vector_type(4)));

// VT layout: [bh][quarter(4)][ 8192 elems ], quarter row stride 232 elems.
constexpr int VT_STRIDE = 232;                 // elems; 464 B = 16B-aligned, 2-way banks
constexpr size_t VT_QELEMS = 8192;             // padded quarter (32 rows x 232 = 7424 used)
constexpr size_t VT_BH = 4 * VT_QELEMS;        // 32768 elems per (b,h)

__device__ __forceinline__ void gl_lds16(const void* g, void* l) {
    __builtin_amdgcn_global_load_lds(
        (const __attribute__((address_space(1))) void*)g,
        (__attribute__((address_space(3))) void*)l, 16, 0, 0);
}

// ---------------- fp32 -> bf16 elementwise convert (x) ----------------
__global__ __launch_bounds__(256)
void cvt_f32_bf16(const float* __restrict__ in, __bf16* __restrict__ out, int n4)
{
    int i = blockIdx.x * 256 + threadIdx.x;
    if (i < n4) {
        float4 v = ((const float4*)in)[i];
        bf16x4 o = { (__bf16)v.x, (__bf16)v.y, (__bf16)v.z, (__bf16)v.w };
        ((bf16x4*)out)[i] = o;
    }
}

// ---------------- W[K][N] fp32 -> WT[N][K] bf16 ----------------
__global__ __launch_bounds__(256)
void transpose_cvt(const float* __restrict__ W, __bf16* __restrict__ WT, int K, int N)
{
    __shared__ float tile[32][33];
    const int n0 = blockIdx.x * 32, k0 = blockIdx.y * 32;
    const int tx = threadIdx.x & 31, ty = threadIdx.x >> 5;
#pragma unroll
    for (int i = ty; i < 32; i += 8)
        tile[i][tx] = W[(size_t)(k0 + i) * N + n0 + tx];
    __syncthreads();
#pragma unroll
    for (int i = ty; i < 32; i += 8)
        WT[(size_t)(n0 + i) * K + k0 + tx] = (__bf16)tile[tx][i];
}

// ---------------- GEMM1: x@Wqkv + BN, LDS-shuffle epilogue ----------------
// v5: double-buffered LDS K-loop (stage t+1 into buf^1 BEFORE computing t from
// buf) -> loads get the whole MFMA phase to land; ONE __syncthreads per K-step
// (its implicit vmcnt(0) drain now only pays the remainder).
// LDS 64 KiB: As dbuf [2][16 KB] @0, Bs dbuf [2][16 KB] @32768.
// Epilogue (unchanged from r4): stages post-BN tile into LDS overlay, writes
// QK as full 128 B lines, V as 16 B chunks along s into VTp.
__global__ __launch_bounds__(256)
void gemm1_bn_scatter(const __bf16* __restrict__ A, const __bf16* __restrict__ BT,
                      const float* __restrict__ bias, const float* __restrict__ gamma,
                      const float* __restrict__ beta, const float* __restrict__ mean,
                      const float* __restrict__ var,
                      __bf16* __restrict__ qkvO, __bf16* __restrict__ VTp)
{
    constexpr int N = QKVD, K = DIN;
    constexpr int BM = 128, BN = 128;
    __shared__ __align__(16) char sm[65536];

    const int t    = threadIdx.x;
    const int wave = t >> 6;
    const int lane = t & 63;
    const int lr   = lane & 15;
    const int q    = lane >> 4;

    constexpr int ntiles = N / BN;           // 12
    // T1: bijective XCD swizzle (nwg = 2352, divisible by 8).
    constexpr int nwg = 196 * ntiles;
    const int bid = (blockIdx.x & 7) * (nwg >> 3) + (blockIdx.x >> 3);
    const int m0 = (bid / ntiles) * BM;
    const int n0 = (bid % ntiles) * BN;
    const int wm = (wave & 1) * 64;
    const int wn = (wave >> 1) * 64;

    const __bf16* aG0 = A  + (size_t)(m0 + (t >> 2)) * K + (t & 3) * 8;
    const __bf16* aG1 = aG0 + (size_t)64 * K;
    const __bf16* bG0 = BT + (size_t)(n0 + (t >> 2)) * K + (t & 3) * 8;
    const __bf16* bG1 = bG0 + (size_t)64 * K;

    // stage one BK=64 tile (A+B) into buffer `cur` (8 x 16 B per thread)
    auto STAGE = [&](int k0, int cur) {
        char* lA = sm + cur * 16384 + wave * 1024;
        char* lB = sm + 32768 + cur * 16384 + wave * 1024;
        gl_lds16(aG0 + k0,      lA);
        gl_lds16(aG1 + k0,      lA + 4096);
        gl_lds16(aG0 + k0 + 32, lA + 8192);
        gl_lds16(aG1 + k0 + 32, lA + 8192 + 4096);
        gl_lds16(bG0 + k0,      lB);
        gl_lds16(bG1 + k0,      lB + 4096);
        gl_lds16(bG0 + k0 + 32, lB + 8192);
        gl_lds16(bG1 + k0 + 32, lB + 8192 + 4096);
    };

    f32x4 acc[4][4] = {};

    STAGE(0, 0);
    __syncthreads();                 // implicit vmcnt(0): buf0 ready
    int cur = 0;
    for (int k0 = 0; k0 < K; k0 += 64) {
        if (k0 + 64 < K) STAGE(k0 + 64, cur ^ 1);   // prefetch next tile
        const __bf16* Abuf = (const __bf16*)(sm + cur * 16384);
        const __bf16* Bbuf = (const __bf16*)(sm + 32768 + cur * 16384);
#pragma unroll
        for (int kk = 0; kk < 2; ++kk) {
            bf16x8 aF[4], bF[4];
#pragma unroll
            for (int i = 0; i < 4; ++i)
                aF[i] = *(const bf16x8*)(Abuf + kk * 4096 + (wm + i * 16 + lr) * 32 + q * 8);
#pragma unroll
            for (int j = 0; j < 4; ++j)
                bF[j] = *(const bf16x8*)(Bbuf + kk * 4096 + (wn + j * 16 + lr) * 32 + q * 8);
#pragma unroll
            for (int i = 0; i < 4; ++i)
#pragma unroll
                for (int j = 0; j < 4; ++j)
                    acc[i][j] = __builtin_amdgcn_mfma_f32_16x16x32_bf16(
                        aF[i], bF[j], acc[i][j], 0, 0, 0);
        }
        __syncthreads();             // reads of buf[cur] done + next tile landed
        cur ^= 1;
    }

    // ---- epilogue: BN + stage to LDS overlay (over the dbuf space) ----
    const int tmod = n0 % 384;
    const int cq0  = (tmod == 0) ? 0 : (tmod == 128 ? 64 : -1);
    const int vc0  = (tmod == 0) ? 64 : 0;
    const int nv   = (tmod == 256) ? 128 : 64;
    const bool qk_wave = (tmod == 0) ? (wn == 0) : (tmod == 128 ? (wn == 64) : false);

    __bf16* qkreg = (__bf16*)sm;                                   // [128][72]
    __bf16* vreg  = (__bf16*)(sm + ((nv == 128) ? 0 : 18432));     // [nv][136] col-major
    const int vbase = (nv == 128) ? wn : 0;

#pragma unroll
    for (int j = 0; j < 4; ++j) {
        const int n = n0 + wn + j * 16 + lr;
        const float s  = gamma[n] * rsqrtf(var[n] + EPSc);
        const float tv = fmaf(bias[n] - mean[n], s, beta[n]);
        if (qk_wave) {
#pragma unroll
            for (int i = 0; i < 4; ++i) {
                const int row = wm + i * 16 + q * 4;
#pragma unroll
                for (int r = 0; r < 4; ++r)
                    qkreg[(row + r) * 72 + j * 16 + lr] = (__bf16)fmaf(acc[i][j][r], s, tv);
            }
        } else {
#pragma unroll
            for (int i = 0; i < 4; ++i) {
                bf16x4 pk = { (__bf16)fmaf(acc[i][j][0], s, tv),
                              (__bf16)fmaf(acc[i][j][1], s, tv),
                              (__bf16)fmaf(acc[i][j][2], s, tv),
                              (__bf16)fmaf(acc[i][j][3], s, tv) };
                *(bf16x4*)(vreg + (vbase + j * 16 + lr) * 136 + wm + i * 16 + q * 4) = pk;
            }
        }
    }
    __syncthreads();

    // ---- QK write-out: full 128 B lines (8 lanes x 16 B) ----
    if (cq0 >= 0) {
#pragma unroll
        for (int rr = 0; rr < 4; ++rr) {
            const int row = rr * 32 + (t >> 3);
            const int l   = t & 7;
            bf16x8 vv = *(const bf16x8*)(qkreg + row * 72 + l * 8);
            *(bf16x8*)(qkvO + (size_t)(m0 + row) * N + n0 + cq0 + l * 8) = vv;
        }
    }
    // ---- V write-out: 16 B along s into VTp ----
    const int iters = (nv * 16) / 256;   // 4 or 8
    for (int it = 0; it < iters; ++it) {
        const int a  = it * 256 + t;
        const int cl = a >> 4;           // local V col
        const int r0 = (a & 15) * 8;     // tile row of first elem
        const int n  = n0 + vc0 + cl;
        const int h  = n / 192;
        const int d  = n - h * 192 - 64;
        const int mr = m0 + r0;
        const int b_ = mr / 196;
        const int s0 = mr - b_ * 196;
        __bf16* dst0 = VTp + (size_t)(b_ * 8 + h) * VT_BH
                     + (size_t)(d >> 5) * VT_QELEMS + (size_t)(d & 31) * VT_STRIDE;
        bf16x8 vv = *(const bf16x8*)(vreg + cl * 136 + r0);
        if (s0 <= 188) {
            *(bf16x8*)(dst0 + s0) = vv;
        } else {
            // chunk straddles a batch boundary (s wraps at 196): scalar split
#pragma unroll
            for (int e = 0; e < 8; ++e) {
                int se = s0 + e;
                __bf16* dst = dst0;
                if (se >= 196) { se -= 196; dst += 8 * VT_BH; }
                dst[se] = vv[e];
            }
        }
    }
}

// ---------------- generic bf16 MFMA GEMM + BN (fp32 out) — GEMM2 ----------------
// v5: same double-buffered single-barrier K-loop as gemm1.
template<int N, int K>
__global__ __launch_bounds__(256)
void gemm_bn_mfma(const __bf16* __restrict__ A, const __bf16* __restrict__ BT,
                  const float* __restrict__ bias, const float* __restrict__ gamma,
                  const float* __restrict__ beta, const float* __restrict__ mean,
                  const float* __restrict__ var, float* __restrict__ C)
{
    constexpr int BM = 128, BN = 128;
    __shared__ __align__(16) char sm[65536];
    const int t    = threadIdx.x;
    const int wave = t >> 6;
    const int lane = t & 63;
    const int lr   = lane & 15;
    const int q    = lane >> 4;
    constexpr int ntiles = N / BN;
    constexpr int nwg = 196 * ntiles;        // 784 for N=512 -> divisible by 8
    const int bid = (blockIdx.x & 7) * (nwg >> 3) + (blockIdx.x >> 3);
    const int m0 = (bid / ntiles) * BM;
    const int n0 = (bid % ntiles) * BN;
    const int wm = (wave & 1) * 64;
    const int wn = (wave >> 1) * 64;
    const __bf16* aG0 = A  + (size_t)(m0 + (t >> 2)) * K + (t & 3) * 8;
    const __bf16* aG1 = aG0 + (size_t)64 * K;
    const __bf16* bG0 = BT + (size_t)(n0 + (t >> 2)) * K + (t & 3) * 8;
    const __bf16* bG1 = bG0 + (size_t)64 * K;

    auto STAGE = [&](int k0, int cur) {
        char* lA = sm + cur * 16384 + wave * 1024;
        char* lB = sm + 32768 + cur * 16384 + wave * 1024;
        gl_lds16(aG0 + k0,      lA);
        gl_lds16(aG1 + k0,      lA + 4096);
        gl_lds16(aG0 + k0 + 32, lA + 8192);
        gl_lds16(aG1 + k0 + 32, lA + 8192 + 4096);
        gl_lds16(bG0 + k0,      lB);
        gl_lds16(bG1 + k0,      lB + 4096);
        gl_lds16(bG0 + k0 + 32, lB + 8192);
        gl_lds16(bG1 + k0 + 32, lB + 8192 + 4096);
    };

    f32x4 acc[4][4] = {};

    STAGE(0, 0);
    __syncthreads();
    int cur = 0;
    for (int k0 = 0; k0 < K; k0 += 64) {
        if (k0 + 64 < K) STAGE(k0 + 64, cur ^ 1);
        const __bf16* Abuf = (const __bf16*)(sm + cur * 16384);
        const __bf16* Bbuf = (const __bf16*)(sm + 32768 + cur * 16384);
#pragma unroll
        for (int kk = 0; kk < 2; ++kk) {
            bf16x8 aF[4], bF[4];
#pragma unroll
            for (int i = 0; i < 4; ++i)
                aF[i] = *(const bf16x8*)(Abuf + kk * 4096 + (wm + i * 16 + lr) * 32 + q * 8);
#pragma unroll
            for (int j = 0; j < 4; ++j)
                bF[j] = *(const bf16x8*)(Bbuf + kk * 4096 + (wn + j * 16 + lr) * 32 + q * 8);
#pragma unroll
            for (int i = 0; i < 4; ++i)
#pragma unroll
                for (int j = 0; j < 4; ++j)
                    acc[i][j] = __builtin_amdgcn_mfma_f32_16x16x32_bf16(
                        aF[i], bF[j], acc[i][j], 0, 0, 0);
        }
        __syncthreads();
        cur ^= 1;
    }
#pragma unroll
    for (int j = 0; j < 4; ++j) {
        const int n = n0 + wn + j * 16 + lr;
        const float s  = gamma[n] * rsqrtf(var[n] + EPSc);
        const float tv = fmaf(bias[n] - mean[n], s, beta[n]);
#pragma unroll
        for (int i = 0; i < 4; ++i) {
            const int mrow = m0 + wm + i * 16 + q * 4;
#pragma unroll
            for (int r = 0; r < 4; ++r)
                C[(size_t)(mrow + r) * N + n] = fmaf(acc[i][j][r], s, tv);
        }
    }
}

// ---------------- MFMA attention v2: one block per (b,h), 16 waves ----------------
// wave w owns q-tile qt = w (16 q-rows); 13 active tiles cover S=196 (pad to 208).
// K staged ONCE, V quarters streamed ONCE each (double-buffered, issue-early).
// LDS: Kb[208][40] (16640 B) | P: 13 x [16][232] (96512 B) | V dbuf 2x16384 = 145920 B
__global__ __launch_bounds__(1024)
void attn_mfma(const __bf16* __restrict__ qkv, const __bf16* __restrict__ VTp,
               __bf16* __restrict__ hidden)
{
    __shared__ __align__(16) char smem[145920];
    __bf16* Kb = (__bf16*)smem;

    const int t = threadIdx.x;
    const int wave = t >> 6, lane = t & 63;
    const int lr = lane & 15, q = lane >> 4;
    const int bh = blockIdx.x;
    const int b = bh >> 3, h = bh & 7;
    const __bf16* qkvb = qkv + (size_t)b * 196 * QKVD + h * 192;

    // ---- issue V quarter 0 stage FIRST so HBM latency drains under K staging ----
    const char* gV = (const char*)(VTp + (size_t)bh * VT_BH);
    char* ldsV = smem + 113152;                 // 2 x 16384 double buffer
    gl_lds16(gV + wave * 1024 + lane * 16, ldsV + wave * 1024);

    // ---- stage K once: rows s=0..195, ch 32..63 -> Kb[s][40] ----
    if (t < 196 * 4) {
        const int s = t >> 2, c = t & 3;
        bf16x8 v = *(const bf16x8*)(qkvb + (size_t)s * QKVD + 32 + c * 8);
        *(bf16x8*)(Kb + s * 40 + c * 8) = v;
    }

    __syncthreads();                            // K ready; barrier drains vmcnt -> V0 ready

    const int qt = wave;                        // q-tile; valid rows only for qt<=12
    const bool wactive = (qt <= 12);
    __bf16* Pw = (__bf16*)(smem + 16640 + (wactive ? qt : 0) * 7424);   // [16][232]

    if (wactive) {
        // Q fragment straight from global
        int sQ = qt * 16 + lr; if (sQ > 195) sQ = 195;
        bf16x8 aQ = *(const bf16x8*)(qkv + ((size_t)b * 196 + sQ) * QKVD + h * 192 + q * 8);

        f32x4 sc[13];
#pragma unroll
        for (int nt = 0; nt < 13; ++nt) {
            bf16x8 bK = *(const bf16x8*)(Kb + (nt * 16 + lr) * 40 + q * 8);
            f32x4 z = {0.f, 0.f, 0.f, 0.f};
            sc[nt] = __builtin_amdgcn_mfma_f32_16x16x32_bf16(aQ, bK, z, 0, 0, 0);
        }
        // ---- register softmax over the 208 cols (cols>=196 masked) ----
        float mrow[4] = {-1e30f, -1e30f, -1e30f, -1e30f};
#pragma unroll
        for (int nt = 0; nt < 13; ++nt) {
            const bool valid = (nt < 12) | (lr < 4);
#pragma unroll
            for (int r = 0; r < 4; ++r) {
                float x = sc[nt][r] * SCALEc;
                sc[nt][r] = x;
                if (valid) mrow[r] = fmaxf(mrow[r], x);
            }
        }
#pragma unroll
        for (int d = 1; d < 16; d <<= 1)
#pragma unroll
            for (int r = 0; r < 4; ++r)
                mrow[r] = fmaxf(mrow[r], __shfl_xor(mrow[r], d, 64));
        float l[4] = {0.f, 0.f, 0.f, 0.f};
#pragma unroll
        for (int nt = 0; nt < 13; ++nt) {
            const bool valid = (nt < 12) | (lr < 4);
#pragma unroll
            for (int r = 0; r < 4; ++r) {
                float e = valid ? __expf(sc[nt][r] - mrow[r]) : 0.f;
                sc[nt][r] = e;
                l[r] += e;
            }
        }
#pragma unroll
        for (int d = 1; d < 16; d <<= 1)
#pragma unroll
            for (int r = 0; r < 4; ++r)
                l[r] += __shfl_xor(l[r], d, 64);
        float inv[4];
#pragma unroll
        for (int r = 0; r < 4; ++r) inv[r] = 1.f / l[r];

        // ---- P to LDS in A-operand layout: P[m=quad*4+r][col] ----
#pragma unroll
        for (int nt = 0; nt < 13; ++nt)
#pragma unroll
            for (int r = 0; r < 4; ++r)
                Pw[(q * 4 + r) * 232 + nt * 16 + lr] = (__bf16)(sc[nt][r] * inv[r]);
        // zero cols 208..231 (PV k-loop reads through col 223)
        for (int idx = lane; idx < 16 * 24; idx += 64) {
            int row = idx & 15, cz = 208 + (idx >> 4);
            Pw[row * 232 + cz] = (__bf16)0.f;
        }
    }
    __syncthreads();                            // P ready (all 13 slots)

    // ---- PV over 4 dv-quarters; next quarter staged under current compute ----
    const int sbase = qt * 16 + q * 4;
    const bool sval = wactive && (sbase + 3 < 196);
    __bf16* hb = hidden + (size_t)b * 200704 + (size_t)h * 25088;

    for (int q4 = 0; q4 < 4; ++q4) {
        const __bf16* Vl = (const __bf16*)(ldsV + (q4 & 1) * 16384);
        if (q4 < 3)   // issue next quarter into the other buffer (drained by the barrier below)
            gl_lds16(gV + (size_t)(q4 + 1) * 16384 + wave * 1024 + lane * 16,
                     ldsV + ((q4 + 1) & 1) * 16384 + wave * 1024);
        if (wactive) {
            f32x4 o0 = {0.f, 0.f, 0.f, 0.f}, o1 = {0.f, 0.f, 0.f, 0.f};
#pragma unroll
            for (int kk = 0; kk < 7; ++kk) {
                bf16x8 aP = *(const bf16x8*)(Pw + lr * 232 + kk * 32 + q * 8);
                bf16x8 b0 = *(const bf16x8*)(Vl + lr * 232 + kk * 32 + q * 8);
                bf16x8 b1 = *(const bf16x8*)(Vl + (16 + lr) * 232 + kk * 32 + q * 8);
                o0 = __builtin_amdgcn_mfma_f32_16x16x32_bf16(aP, b0, o0, 0, 0, 0);
                o1 = __builtin_amdgcn_mfma_f32_16x16x32_bf16(aP, b1, o1, 0, 0, 0);
            }
            if (sval) {
#pragma unroll
                for (int nt2 = 0; nt2 < 2; ++nt2) {
                    f32x4 o = nt2 ? o1 : o0;
                    const int d = q4 * 32 + nt2 * 16 + lr;
                    bf16x4 pk;
#pragma unroll
                    for (int r = 0; r < 4; ++r) {
                        float x = o[r];
                        pk[r] = (__bf16)(x * fminf(fmaxf(x + 3.f, 0.f), 6.f) * (1.f / 6.f));
                    }
                    *(bf16x4*)(hb + (size_t)d * 196 + sbase) = pk;
                }
            }
        }
        if (q4 < 3) __syncthreads();
    }
}

} // namespace

extern "C" void kernel_launch(void* const* d_in, const int* in_sizes, int n_in,
                              void* d_out, int out_size, void* d_ws, size_t ws_size,
                              hipStream_t stream)
{
    const float* x    = (const float*)d_in[0];
    const float* Wqkv = (const float*)d_in[1];
    const float* bqkv = (const float*)d_in[2];
    const float* g1   = (const float*)d_in[3];
    const float* be1  = (const float*)d_in[4];
    const float* mu1  = (const float*)d_in[5];
    const float* va1  = (const float*)d_in[6];
    const float* Wp   = (const float*)d_in[7];
    const float* bp   = (const float*)d_in[8];
    const float* g2   = (const float*)d_in[9];
    const float* be2  = (const float*)d_in[10];
    const float* mu2  = (const float*)d_in[11];
    const float* va2  = (const float*)d_in[12];

    // workspace layout (bytes)
    char* ws = (char*)d_ws;
    __bf16* qkv    = (__bf16*)ws;                    // 25088*1536*2 = 77,070,336
    __bf16* VTp    = (__bf16*)(ws + 77070336);       // 1024*32768*2 = 67,108,864
    __bf16* hidden = (__bf16*)(ws + 144179200);      // 25088*1024*2 = 51,380,224
    __bf16* xb     = (__bf16*)(ws + 195559424);      // 25088*512*2  = 25,690,112
    __bf16* WT1    = (__bf16*)(ws + 221249536);      // 1536*512*2
    __bf16* WT2    = (__bf16*)(ws + 222822400);      // 512*1024*2
    float*  out    = (float*)d_out;

    cvt_f32_bf16<<<dim3((Mrows * DIN / 4 + 255) / 256), dim3(256), 0, stream>>>(
        x, xb, Mrows * DIN / 4);
    transpose_cvt<<<dim3(QKVD / 32, DIN / 32), dim3(256), 0, stream>>>(Wqkv, WT1, DIN, QKVD);
    transpose_cvt<<<dim3(DIN / 32, PIN / 32), dim3(256), 0, stream>>>(Wp, WT2, PIN, DIN);

    // GEMM1 + BN -> qkv bf16 (Q,K) + VTp (V pre-transposed)
    gemm1_bn_scatter<<<dim3(196 * (QKVD / 128)), dim3(256), 0, stream>>>(
        xb, WT1, bqkv, g1, be1, mu1, va1, qkv, VTp);

    // MFMA attention -> hidden bf16 (scrambled layout); 1 block per (b,h), 16 waves
    attn_mfma<<<dim3(Bb * Hh), dim3(1024), 0, stream>>>(qkv, VTp, hidden);

    // GEMM2 + BN -> out fp32
    gemm_bn_mfma<DIN, PIN><<<dim3(196 * (DIN / 128)), dim3(256), 0, stream>>>(
        hidden, WT2, bp, g2, be2, mu2, va2, out);
}